// Round 1
// baseline (1075.322 us; speedup 1.0000x reference)
//
#include <hip/hip_runtime.h>
#include <hip/hip_bf16.h>
#include <math.h>

#define B_  128
#define L_  196
#define F_  2048
#define H_  512
#define A_  512
#define ML_ (B_*L_)   // 25088 rows, = 196 tiles of 128 exactly

// ---------------------------------------------------------------------------
// K1: dec[b][a] = b_dec[a] + b_enc[a] + sum_h hs[b][h] * Wdec[a][h]
//     (b_enc folded in so k_scores epilogue adds a single term)
//     Also zeroes the scores accumulator (d_ws is poisoned 0xAA each call).
// ---------------------------------------------------------------------------
__global__ __launch_bounds__(256) void k_dec(const float* __restrict__ hs,
                                             const float* __restrict__ Wdec,
                                             const float* __restrict__ bdec,
                                             const float* __restrict__ benc,
                                             float* __restrict__ dec,
                                             float* __restrict__ scores) {
  const int b = blockIdx.x, t = threadIdx.x;
  const int g = b * 256 + t;
  if (g < ML_) scores[g] = 0.f;

  __shared__ float h[H_];
  h[t]       = hs[b * H_ + t];
  h[t + 256] = hs[b * H_ + t + 256];
  __syncthreads();

#pragma unroll
  for (int r = 0; r < 2; r++) {
    const int a = t + r * 256;
    float acc = bdec[a] + benc[a];
    const float4* wr = (const float4*)(Wdec + (size_t)a * H_);
#pragma unroll 4
    for (int k4 = 0; k4 < H_ / 4; k4++) {
      const float4 w = wr[k4];
      acc += w.x * h[4*k4] + w.y * h[4*k4+1] + w.z * h[4*k4+2] + w.w * h[4*k4+3];
    }
    dec[b * A_ + a] = acc;
  }
}

// ---------------------------------------------------------------------------
// K2: scores[m] += sum_{a in tile} relu(feat[m,:]·Wenc[a,:] + dec[b,a]) * wcom[a]
//     128x128 tile, 256 threads, 8x8 micro-tile per thread, K_T=16.
//     M = 25088 = 196*128 exact; A = 512 = 4*128 exact; F = 2048 = 128*16 exact.
// ---------------------------------------------------------------------------
__global__ __launch_bounds__(256) void k_scores(const float* __restrict__ feat,
                                                const float* __restrict__ Wenc,
                                                const float* __restrict__ dec,
                                                const float* __restrict__ wcom,
                                                float* __restrict__ scores) {
  __shared__ float As[16][128];   // [k][m]
  __shared__ float Bs[16][128];   // [k][a]

  const int tid = threadIdx.x;
  const int m0 = blockIdx.x * 128;
  const int a0 = blockIdx.y * 128;
  const int tx = tid & 15;        // a-direction (8 cols each)
  const int ty = tid >> 4;        // m-direction (8 rows each)

  float acc[8][8];
#pragma unroll
  for (int i = 0; i < 8; i++) {
#pragma unroll
    for (int j = 0; j < 8; j++) acc[i][j] = 0.f;
  }

  for (int kt = 0; kt < F_; kt += 16) {
    // stage A (features) and B (Wenc) tiles, transposed to [k][row]
#pragma unroll
    for (int rep = 0; rep < 2; rep++) {
      const int idx = rep * 256 + tid;
      const int row = idx >> 2;
      const int kp  = (idx & 3) << 2;
      const float4 v = *(const float4*)(feat + (size_t)(m0 + row) * F_ + kt + kp);
      As[kp+0][row] = v.x; As[kp+1][row] = v.y; As[kp+2][row] = v.z; As[kp+3][row] = v.w;
      const float4 w = *(const float4*)(Wenc + (size_t)(a0 + row) * F_ + kt + kp);
      Bs[kp+0][row] = w.x; Bs[kp+1][row] = w.y; Bs[kp+2][row] = w.z; Bs[kp+3][row] = w.w;
    }
    __syncthreads();

#pragma unroll
    for (int k = 0; k < 16; k++) {
      float ar[8], br[8];
      *(float4*)&ar[0] = *(const float4*)&As[k][ty * 8];
      *(float4*)&ar[4] = *(const float4*)&As[k][ty * 8 + 4];
      *(float4*)&br[0] = *(const float4*)&Bs[k][tx * 8];
      *(float4*)&br[4] = *(const float4*)&Bs[k][tx * 8 + 4];
#pragma unroll
      for (int i = 0; i < 8; i++) {
#pragma unroll
        for (int j = 0; j < 8; j++) acc[i][j] = fmaf(ar[i], br[j], acc[i][j]);
      }
    }
    __syncthreads();
  }

  // Epilogue: relu(acc + dec) · wcom, reduce the 128 a-columns of this tile.
  float w8[8];
  *(float4*)&w8[0] = *(const float4*)(wcom + a0 + tx * 8);
  *(float4*)&w8[4] = *(const float4*)(wcom + a0 + tx * 8 + 4);

#pragma unroll
  for (int i = 0; i < 8; i++) {
    const int m = m0 + ty * 8 + i;
    const int b = m / L_;
    const float* dp = dec + b * A_ + a0 + tx * 8;
    float p = 0.f;
#pragma unroll
    for (int j = 0; j < 8; j++) {
      const float e = acc[i][j] + dp[j];
      p = fmaf(fmaxf(e, 0.f), w8[j], p);
    }
    // reduce across the 16 tx lanes (lane bits 0..3)
    p += __shfl_xor(p, 1);
    p += __shfl_xor(p, 2);
    p += __shfl_xor(p, 4);
    p += __shfl_xor(p, 8);
    if (tx == 0) atomicAdd(&scores[m], p);
  }
}

// ---------------------------------------------------------------------------
// K3: alpha[b,:] = softmax(scores[b,:]) over L=196  (b_com shift is
//     softmax-invariant, so it is dropped entirely)
// ---------------------------------------------------------------------------
__global__ __launch_bounds__(256) void k_softmax(const float* __restrict__ scores,
                                                 float* __restrict__ alpha) {
  const int b = blockIdx.x, t = threadIdx.x;
  __shared__ float redm[4];
  __shared__ float reds[4];

  float s = (t < L_) ? scores[b * L_ + t] : -INFINITY;

  float m = s;
#pragma unroll
  for (int o = 32; o >= 1; o >>= 1) m = fmaxf(m, __shfl_xor(m, o));
  if ((t & 63) == 0) redm[t >> 6] = m;
  __syncthreads();
  m = fmaxf(fmaxf(redm[0], redm[1]), fmaxf(redm[2], redm[3]));

  float e = (t < L_) ? expf(s - m) : 0.f;
  float sum = e;
#pragma unroll
  for (int o = 32; o >= 1; o >>= 1) sum += __shfl_xor(sum, o);
  if ((t & 63) == 0) reds[t >> 6] = sum;
  __syncthreads();
  sum = reds[0] + reds[1] + reds[2] + reds[3];

  if (t < L_) alpha[b * L_ + t] = e / sum;
}

// ---------------------------------------------------------------------------
// K4: out[b][f] = sum_l feat[b][l][f] * alpha[b][l]
// ---------------------------------------------------------------------------
__global__ __launch_bounds__(256) void k_wsum(const float* __restrict__ feat,
                                              const float* __restrict__ alpha,
                                              float* __restrict__ out) {
  const int fc = blockIdx.x;     // 8 chunks of 256 floats
  const int b  = blockIdx.y;
  const int t  = threadIdx.x;

  __shared__ float al[L_];
  for (int i = t; i < L_; i += 256) al[i] = alpha[b * L_ + i];
  __syncthreads();

  const int f = fc * 256 + t;
  const float* fp = feat + (size_t)b * L_ * F_ + f;
  float acc = 0.f;
#pragma unroll 4
  for (int l = 0; l < L_; l++) acc = fmaf(fp[(size_t)l * F_], al[l], acc);
  out[b * F_ + f] = acc;
}

// ---------------------------------------------------------------------------
extern "C" void kernel_launch(void* const* d_in, const int* in_sizes, int n_in,
                              void* d_out, int out_size, void* d_ws, size_t ws_size,
                              hipStream_t stream) {
  const float* feat = (const float*)d_in[0];   // [B,L,F]
  const float* hs   = (const float*)d_in[1];   // [B,H]
  const float* Wenc = (const float*)d_in[2];   // [A,F]
  const float* benc = (const float*)d_in[3];   // [A]
  const float* Wdec = (const float*)d_in[4];   // [A,H]
  const float* bdec = (const float*)d_in[5];   // [A]
  const float* wcom = (const float*)d_in[6];   // [1,A]
  // d_in[7] = b_com: softmax-invariant, unused

  float* out   = (float*)d_out;                // [B*F] weighted ++ [B*L] alpha
  float* alpha = out + B_ * F_;                // second output region
  float* dec    = (float*)d_ws;                // [B*A]
  float* scores = dec + B_ * A_;               // [B*L]

  k_dec<<<dim3(B_), dim3(256), 0, stream>>>(hs, Wdec, bdec, benc, dec, scores);
  k_scores<<<dim3(ML_ / 128, A_ / 128), dim3(256), 0, stream>>>(feat, Wenc, dec, wcom, scores);
  k_softmax<<<dim3(B_), dim3(256), 0, stream>>>(scores, alpha);
  k_wsum<<<dim3(F_ / 256, B_), dim3(256), 0, stream>>>(feat, alpha, out);
}

// Round 2
// 470.442 us; speedup vs baseline: 2.2858x; 2.2858x over previous
//
#include <hip/hip_runtime.h>
#include <hip/hip_bf16.h>
#include <math.h>

#define B_  128
#define L_  196
#define F_  2048
#define H_  512
#define A_  512
#define ML_ (B_*L_)   // 25088 rows, = 196 tiles of 128 exactly

typedef _Float16 half8 __attribute__((ext_vector_type(8)));
typedef _Float16 half4v __attribute__((ext_vector_type(4)));
typedef float f32x4 __attribute__((ext_vector_type(4)));

// async 16B global->LDS (LDS dest = wave-uniform base + lane*16)
__device__ __forceinline__ void gld_lds16(const void* g, void* l) {
  __builtin_amdgcn_global_load_lds((const __attribute__((address_space(1))) void*)g,
                                   (__attribute__((address_space(3))) void*)l, 16, 0, 0);
}

// ---------------------------------------------------------------------------
// K1: dec[b][a] = b_dec[a] + b_enc[a] + sum_h hs[b][h] * Wdec[a][h]
//     Also zeroes the scores accumulator (ws is re-poisoned each call).
// ---------------------------------------------------------------------------
__global__ __launch_bounds__(256) void k_dec(const float* __restrict__ hs,
                                             const float* __restrict__ Wdec,
                                             const float* __restrict__ bdec,
                                             const float* __restrict__ benc,
                                             float* __restrict__ dec,
                                             float* __restrict__ scores) {
  const int b = blockIdx.x, t = threadIdx.x;
  const int g = b * 256 + t;
  if (g < ML_) scores[g] = 0.f;

  __shared__ float h[H_];
  h[t]       = hs[b * H_ + t];
  h[t + 256] = hs[b * H_ + t + 256];
  __syncthreads();

#pragma unroll
  for (int r = 0; r < 2; r++) {
    const int a = t + r * 256;
    float acc = bdec[a] + benc[a];
    const float4* wr = (const float4*)(Wdec + (size_t)a * H_);
#pragma unroll 4
    for (int k4 = 0; k4 < H_ / 4; k4++) {
      const float4 w = wr[k4];
      acc += w.x * h[4*k4] + w.y * h[4*k4+1] + w.z * h[4*k4+2] + w.w * h[4*k4+3];
    }
    dec[b * A_ + a] = acc;
  }
}

// ---------------------------------------------------------------------------
// K_cvt: fp32 -> fp16, vectorized grid-stride
// ---------------------------------------------------------------------------
__global__ __launch_bounds__(256) void k_cvt(const float4* __restrict__ src,
                                             half4v* __restrict__ dst, int n4) {
  for (int i = blockIdx.x * 256 + threadIdx.x; i < n4; i += gridDim.x * 256) {
    const float4 v = src[i];
    half4v o = { (_Float16)v.x, (_Float16)v.y, (_Float16)v.z, (_Float16)v.w };
    dst[i] = o;
  }
}

// ---------------------------------------------------------------------------
// K2 (MFMA): scores[m] += sum_a relu(feat[m,:]·Wenc[a,:] + dec[b,a]) * wcom[a]
//   128x128 tile, BK=64 halves, 16x16x32 f16 MFMA, 4 waves in 2x2,
//   global_load_lds width-16 staging with XOR-swizzled 16B granules:
//   granule (row, pos) holds global chunk c with pos = c ^ (row & 7).
// ---------------------------------------------------------------------------
__global__ __launch_bounds__(256) void k_scores_mfma(const _Float16* __restrict__ fA,
                                                     const _Float16* __restrict__ fB,
                                                     const float* __restrict__ dec,
                                                     const float* __restrict__ wcom,
                                                     float* __restrict__ scores) {
  __shared__ _Float16 As[128 * 64];
  __shared__ _Float16 Bs[128 * 64];
  __shared__ float decS[2][128];

  const int tid  = threadIdx.x;
  const int lane = tid & 63;
  const int w    = tid >> 6;
  const int a0   = blockIdx.x * 128;   // a-tiles vary fastest -> feat tile reused from LLC
  const int m0   = blockIdx.y * 128;
  const int wm   = w & 1;
  const int wn   = w >> 1;
  const int quad = lane >> 4;
  const int l16  = lane & 15;

  f32x4 acc[4][4];
#pragma unroll
  for (int i = 0; i < 4; i++)
#pragma unroll
    for (int j = 0; j < 4; j++)
#pragma unroll
      for (int k = 0; k < 4; k++) acc[i][j][k] = 0.f;

  // staging lane geometry (8 rows x 8 chunks per wave-issue)
  const int srow   = lane >> 3;            // 0..7 row within 8-row group
  const int schunk = (lane & 7) ^ srow;    // global 8-half chunk to fetch
  const _Float16* gAb = fA + (size_t)(m0 + srow) * F_ + schunk * 8;
  const _Float16* gBb = fB + (size_t)(a0 + srow) * F_ + schunk * 8;

  for (int kt = 0; kt < F_; kt += 64) {
#pragma unroll
    for (int i = 0; i < 4; i++) {
      const int r = w * 32 + i * 8;        // base row of this 8-row group
      gld_lds16(gAb + (size_t)r * F_ + kt, &As[r * 64]);
      gld_lds16(gBb + (size_t)r * F_ + kt, &Bs[r * 64]);
    }
    __syncthreads();

#pragma unroll
    for (int k32 = 0; k32 < 2; k32++) {
      half8 af[4], bf[4];
#pragma unroll
      for (int mt = 0; mt < 4; mt++) {
        const int row = wm * 64 + mt * 16 + l16;
        const int pos = (k32 * 4 + quad) ^ (row & 7);
        af[mt] = *(const half8*)&As[row * 64 + pos * 8];
      }
#pragma unroll
      for (int at = 0; at < 4; at++) {
        const int row = wn * 64 + at * 16 + l16;
        const int pos = (k32 * 4 + quad) ^ (row & 7);
        bf[at] = *(const half8*)&Bs[row * 64 + pos * 8];
      }
#pragma unroll
      for (int mt = 0; mt < 4; mt++)
#pragma unroll
        for (int at = 0; at < 4; at++)
          acc[mt][at] = __builtin_amdgcn_mfma_f32_16x16x32_f16(af[mt], bf[at], acc[mt][at], 0, 0, 0);
    }
    __syncthreads();
  }

  // Epilogue: stage the (at most 2) dec rows this m-tile touches into LDS.
  const int b0 = m0 / L_;
  {
    const int i = tid >> 7;                 // 0..1
    const int j = tid & 127;
    int bb = b0 + i; if (bb > B_ - 1) bb = B_ - 1;
    decS[i][j] = dec[bb * A_ + a0 + j];
  }
  __syncthreads();

  float w4[4];
#pragma unroll
  for (int at = 0; at < 4; at++) w4[at] = wcom[a0 + wn * 64 + at * 16 + l16];

#pragma unroll
  for (int mt = 0; mt < 4; mt++) {
#pragma unroll
    for (int r = 0; r < 4; r++) {
      const int m  = m0 + wm * 64 + mt * 16 + quad * 4 + r;  // C/D: row=(lane>>4)*4+reg
      const int db = m / L_ - b0;                            // 0 or 1
      float p = 0.f;
#pragma unroll
      for (int at = 0; at < 4; at++) {
        const float e = acc[mt][at][r] + decS[db][wn * 64 + at * 16 + l16];
        p = fmaf(fmaxf(e, 0.f), w4[at], p);
      }
      p += __shfl_xor(p, 1);
      p += __shfl_xor(p, 2);
      p += __shfl_xor(p, 4);
      p += __shfl_xor(p, 8);
      if (l16 == 0) atomicAdd(&scores[m], p);
    }
  }
}

// ---------------------------------------------------------------------------
// K2-fallback (fp32 register-tile) if workspace can't hold the f16 copies
// ---------------------------------------------------------------------------
__global__ __launch_bounds__(256) void k_scores(const float* __restrict__ feat,
                                                const float* __restrict__ Wenc,
                                                const float* __restrict__ dec,
                                                const float* __restrict__ wcom,
                                                float* __restrict__ scores) {
  __shared__ float As[16][128];
  __shared__ float Bs[16][128];

  const int tid = threadIdx.x;
  const int m0 = blockIdx.x * 128;
  const int a0 = blockIdx.y * 128;
  const int tx = tid & 15;
  const int ty = tid >> 4;

  float acc[8][8];
#pragma unroll
  for (int i = 0; i < 8; i++)
#pragma unroll
    for (int j = 0; j < 8; j++) acc[i][j] = 0.f;

  for (int kt = 0; kt < F_; kt += 16) {
#pragma unroll
    for (int rep = 0; rep < 2; rep++) {
      const int idx = rep * 256 + tid;
      const int row = idx >> 2;
      const int kp  = (idx & 3) << 2;
      const float4 v = *(const float4*)(feat + (size_t)(m0 + row) * F_ + kt + kp);
      As[kp+0][row] = v.x; As[kp+1][row] = v.y; As[kp+2][row] = v.z; As[kp+3][row] = v.w;
      const float4 w = *(const float4*)(Wenc + (size_t)(a0 + row) * F_ + kt + kp);
      Bs[kp+0][row] = w.x; Bs[kp+1][row] = w.y; Bs[kp+2][row] = w.z; Bs[kp+3][row] = w.w;
    }
    __syncthreads();

#pragma unroll
    for (int k = 0; k < 16; k++) {
      float ar[8], br[8];
      *(float4*)&ar[0] = *(const float4*)&As[k][ty * 8];
      *(float4*)&ar[4] = *(const float4*)&As[k][ty * 8 + 4];
      *(float4*)&br[0] = *(const float4*)&Bs[k][tx * 8];
      *(float4*)&br[4] = *(const float4*)&Bs[k][tx * 8 + 4];
#pragma unroll
      for (int i = 0; i < 8; i++)
#pragma unroll
        for (int j = 0; j < 8; j++) acc[i][j] = fmaf(ar[i], br[j], acc[i][j]);
    }
    __syncthreads();
  }

  float w8[8];
  *(float4*)&w8[0] = *(const float4*)(wcom + a0 + tx * 8);
  *(float4*)&w8[4] = *(const float4*)(wcom + a0 + tx * 8 + 4);

#pragma unroll
  for (int i = 0; i < 8; i++) {
    const int m = m0 + ty * 8 + i;
    const int b = m / L_;
    const float* dp = dec + b * A_ + a0 + tx * 8;
    float p = 0.f;
#pragma unroll
    for (int j = 0; j < 8; j++) {
      const float e = acc[i][j] + dp[j];
      p = fmaf(fmaxf(e, 0.f), w8[j], p);
    }
    p += __shfl_xor(p, 1);
    p += __shfl_xor(p, 2);
    p += __shfl_xor(p, 4);
    p += __shfl_xor(p, 8);
    if (tx == 0) atomicAdd(&scores[m], p);
  }
}

// ---------------------------------------------------------------------------
// K3: alpha[b,:] = softmax(scores[b,:]) over L=196
// ---------------------------------------------------------------------------
__global__ __launch_bounds__(256) void k_softmax(const float* __restrict__ scores,
                                                 float* __restrict__ alpha) {
  const int b = blockIdx.x, t = threadIdx.x;
  __shared__ float redm[4];
  __shared__ float reds[4];

  float s = (t < L_) ? scores[b * L_ + t] : -INFINITY;

  float m = s;
#pragma unroll
  for (int o = 32; o >= 1; o >>= 1) m = fmaxf(m, __shfl_xor(m, o));
  if ((t & 63) == 0) redm[t >> 6] = m;
  __syncthreads();
  m = fmaxf(fmaxf(redm[0], redm[1]), fmaxf(redm[2], redm[3]));

  float e = (t < L_) ? expf(s - m) : 0.f;
  float sum = e;
#pragma unroll
  for (int o = 32; o >= 1; o >>= 1) sum += __shfl_xor(sum, o);
  if ((t & 63) == 0) reds[t >> 6] = sum;
  __syncthreads();
  sum = reds[0] + reds[1] + reds[2] + reds[3];

  if (t < L_) alpha[b * L_ + t] = e / sum;
}

// ---------------------------------------------------------------------------
// K4: out[b][f] = sum_l feat[b][l][f] * alpha[b][l]
// ---------------------------------------------------------------------------
__global__ __launch_bounds__(256) void k_wsum(const float* __restrict__ feat,
                                              const float* __restrict__ alpha,
                                              float* __restrict__ out) {
  const int fc = blockIdx.x;
  const int b  = blockIdx.y;
  const int t  = threadIdx.x;

  __shared__ float al[L_];
  for (int i = t; i < L_; i += 256) al[i] = alpha[b * L_ + i];
  __syncthreads();

  const int f = fc * 256 + t;
  const float* fp = feat + (size_t)b * L_ * F_ + f;
  float acc = 0.f;
#pragma unroll 4
  for (int l = 0; l < L_; l++) acc = fmaf(fp[(size_t)l * F_], al[l], acc);
  out[b * F_ + f] = acc;
}

// ---------------------------------------------------------------------------
extern "C" void kernel_launch(void* const* d_in, const int* in_sizes, int n_in,
                              void* d_out, int out_size, void* d_ws, size_t ws_size,
                              hipStream_t stream) {
  const float* feat = (const float*)d_in[0];   // [B,L,F]
  const float* hs   = (const float*)d_in[1];   // [B,H]
  const float* Wenc = (const float*)d_in[2];   // [A,F]
  const float* benc = (const float*)d_in[3];   // [A]
  const float* Wdec = (const float*)d_in[4];   // [A,H]
  const float* bdec = (const float*)d_in[5];   // [A]
  const float* wcom = (const float*)d_in[6];   // [1,A]
  // d_in[7] = b_com: softmax-invariant, unused

  float* out   = (float*)d_out;                // [B*F] weighted ++ [B*L] alpha
  float* alpha = out + B_ * F_;
  float* dec    = (float*)d_ws;                // [B*A]
  float* scores = dec + B_ * A_;               // [B*L]

  const size_t need = (size_t)(B_ * A_ + ML_) * 4
                    + ((size_t)ML_ * F_ + (size_t)A_ * F_) * 2;

  k_dec<<<dim3(B_), dim3(256), 0, stream>>>(hs, Wdec, bdec, benc, dec, scores);

  if (ws_size >= need) {
    _Float16* fH = (_Float16*)(scores + ML_);            // [ML_, F_] fp16
    _Float16* wH = fH + (size_t)ML_ * F_;                // [A_, F_] fp16
    k_cvt<<<dim3(4096), dim3(256), 0, stream>>>((const float4*)feat, (half4v*)fH, ML_ * F_ / 4);
    k_cvt<<<dim3(256),  dim3(256), 0, stream>>>((const float4*)Wenc, (half4v*)wH, A_ * F_ / 4);
    k_scores_mfma<<<dim3(A_ / 128, ML_ / 128), dim3(256), 0, stream>>>(fH, wH, dec, wcom, scores);
  } else {
    k_scores<<<dim3(ML_ / 128, A_ / 128), dim3(256), 0, stream>>>(feat, Wenc, dec, wcom, scores);
  }

  k_softmax<<<dim3(B_), dim3(256), 0, stream>>>(scores, alpha);
  k_wsum<<<dim3(F_ / 256, B_), dim3(256), 0, stream>>>(feat, alpha, out);
}